// Round 14
// baseline (34.224 us; speedup 1.0000x reference)
//
#include <hip/hip_runtime.h>

// out[b,s,h,w] = sum_t input[b,s,t,h,w] * weight[t, h%8, w%8]   (h,w < 256; else 0)
// output[b, s*1024 + i*32 + j, q*16 + p] = out[b,s, 8i+p, 8j+q]   i,j in [0,32), p,q in [0,16)
//
// Round-14: R12 geometry (1024 blocks x 256 thr, block g owns image rows
// [8g,8g+8)) restructured as a 2-quad intra-block pipeline with lgkm-only
// barriers (no vmcnt drains anywhere):
//   loads0 -> stage weights (overlap) -> lgkm_bar -> fma0 -> commit tile0
//   -> loads1 issued -> lgkm_bar -> stores0 (under in-flight loads1)
//   -> fma1 -> commit tile1 -> lgkm_bar -> stores1
// Quad Q = rows 8g+4Q..+3 -> p-quad pp=4Q of (i=g, p<8) and pp+8 of (i=g-1).
// 16B p-contiguous store grains, clustered per block (merge proven R9/R12/R13).

namespace {

constexpr int TT   = 16;
constexpr int LDSW = 268;   // 264 cols + 4 pad

typedef float fvec4 __attribute__((ext_vector_type(4)));

// Barrier waiting only LDS ops: global loads/stores stay in flight across it.
__device__ __forceinline__ void lgkm_barrier() {
    __builtin_amdgcn_sched_barrier(0);
    asm volatile("s_waitcnt lgkmcnt(0)" ::: "memory");
    __builtin_amdgcn_s_barrier();
    __builtin_amdgcn_sched_barrier(0);
}

__global__ __launch_bounds__(256, 4) void meas_kernel(
    const float* __restrict__ in, const float* __restrict__ wt,
    float* __restrict__ out)
{
    __shared__ float tile[2][4 * LDSW];
    __shared__ float wlds[TT * 64];

    const int tid = threadIdx.x;

    // XCD swizzle: 1024 blocks, 8 XCDs -> 128 logical blocks (one b) per XCD;
    // g-neighbors (output line partners) adjacent -> co-XCD, co-time.
    const int bid = (blockIdx.x & 7) * 128 + (blockIdx.x >> 3);
    const int g = bid & 31;
    const int s = (bid >> 5) & 3;
    const int b = bid >> 7;

    const float* __restrict__ inp = in + (size_t)(b * 4 + s) * TT * 65536;
    float* __restrict__ outb = out + ((size_t)b * 4096 + (size_t)s * 1024) * 256;

    const int r = tid >> 6;        // 0..3 (wave-uniform row within quad)
    const int c = tid & 63;
    const int w = c * 4;
    const int h0 = g * 8 + r;      // quad0 row

    // ---- issue quad0 loads first (16KB/wave in flight during staging) ----
    float4 v[TT];
    {
        const float* gp = inp + h0 * 256 + w;
#pragma unroll
        for (int t = 0; t < TT; ++t)
            v[t] = *reinterpret_cast<const float4*>(gp + t * 65536);
    }
    __builtin_amdgcn_sched_barrier(0);

    // ---- stage weights + halo-col zeros (overlaps quad0 loads) ----
    for (int idx = tid; idx < TT * 64; idx += 256) wlds[idx] = wt[idx];
    if (tid < 16) {   // 2 tiles x 4 rows x 2 c4-slots (cols 256..263)
        const int tq = tid >> 3;
        const int r4 = (tid >> 1) & 3;
        const int c4 = 64 + (tid & 1);
        *reinterpret_cast<float4*>(&tile[tq][r4 * LDSW + c4 * 4]) =
            make_float4(0.f, 0.f, 0.f, 0.f);
    }

    lgkm_barrier();   // weights + halos visible; quad0 loads still flying

    // ---- fma0 + commit tile0 ----
    {
        const float* wrow = &wlds[(h0 & 7) * 8 + (w & 7)];
        float4 acc = make_float4(0.f, 0.f, 0.f, 0.f);
#pragma unroll
        for (int t = 0; t < TT; ++t) {
            const float4 wv = *reinterpret_cast<const float4*>(wrow + t * 64);
            acc.x += v[t].x * wv.x;
            acc.y += v[t].y * wv.y;
            acc.z += v[t].z * wv.z;
            acc.w += v[t].w * wv.w;
        }
        *reinterpret_cast<float4*>(&tile[0][r * LDSW + w]) = acc;
    }

    // ---- issue quad1 loads (regs reused; in flight across barrier+stores0) ----
    const int h1 = h0 + 4;
    {
        const float* gp = inp + h1 * 256 + w;
#pragma unroll
        for (int t = 0; t < TT; ++t)
            v[t] = *reinterpret_cast<const float4*>(gp + t * 65536);
    }
    __builtin_amdgcn_sched_barrier(0);

    lgkm_barrier();   // tile0 visible; quad1 loads still flying

    // ---- stores quad0 (pp = 0): fly under quad1 loads ----
#pragma unroll
    for (int m2 = 0; m2 < 2; ++m2) {
        const int u  = m2 * 256 + tid;   // 0..511
        const int j  = u >> 4;           // 0..31
        const int q2 = u & 15;           // 0..15
        const float* src = &tile[0][j * 8 + q2];
        const float4 a4 = make_float4(src[0], src[LDSW], src[2 * LDSW], src[3 * LDSW]);
        // A: window-row i=g, p = 0..3
        *reinterpret_cast<float4*>(outb + (size_t)(g * 32 + j) * 256 + q2 * 16) = a4;
        // B: window-row i=g-1, p = 8..11
        if (g > 0)
            *reinterpret_cast<float4*>(outb + (size_t)((g - 1) * 32 + j) * 256 + q2 * 16 + 8) = a4;
        // pad: i=31, p = 8..11 (image rows 256..259 = zeros), owned by g==31
        if (g == 31)
            *reinterpret_cast<float4*>(outb + (size_t)(992 + j) * 256 + q2 * 16 + 8) =
                make_float4(0.f, 0.f, 0.f, 0.f);
    }

    // ---- fma1 + commit tile1 ----
    {
        const float* wrow = &wlds[(h1 & 7) * 8 + (w & 7)];
        float4 acc = make_float4(0.f, 0.f, 0.f, 0.f);
#pragma unroll
        for (int t = 0; t < TT; ++t) {
            const float4 wv = *reinterpret_cast<const float4*>(wrow + t * 64);
            acc.x += v[t].x * wv.x;
            acc.y += v[t].y * wv.y;
            acc.z += v[t].z * wv.z;
            acc.w += v[t].w * wv.w;
        }
        *reinterpret_cast<float4*>(&tile[1][r * LDSW + w]) = acc;
    }

    lgkm_barrier();   // tile1 visible

    // ---- stores quad1 (pp = 4) ----
#pragma unroll
    for (int m2 = 0; m2 < 2; ++m2) {
        const int u  = m2 * 256 + tid;
        const int j  = u >> 4;
        const int q2 = u & 15;
        const float* src = &tile[1][j * 8 + q2];
        const float4 a4 = make_float4(src[0], src[LDSW], src[2 * LDSW], src[3 * LDSW]);
        // A: window-row i=g, p = 4..7
        *reinterpret_cast<float4*>(outb + (size_t)(g * 32 + j) * 256 + q2 * 16 + 4) = a4;
        // B: window-row i=g-1, p = 12..15
        if (g > 0)
            *reinterpret_cast<float4*>(outb + (size_t)((g - 1) * 32 + j) * 256 + q2 * 16 + 12) = a4;
        // pad: i=31, p = 12..15, owned by g==31
        if (g == 31)
            *reinterpret_cast<float4*>(outb + (size_t)(992 + j) * 256 + q2 * 16 + 12) =
                make_float4(0.f, 0.f, 0.f, 0.f);
    }
}

} // namespace

extern "C" void kernel_launch(void* const* d_in, const int* in_sizes, int n_in,
                              void* d_out, int out_size, void* d_ws, size_t ws_size,
                              hipStream_t stream) {
    const float* in = (const float*)d_in[0];
    const float* wt = (const float*)d_in[1];
    float* out      = (float*)d_out;
    hipLaunchKernelGGL(meas_kernel, dim3(1024), dim3(256), 0, stream, in, wt, out);
}

// Round 15
// 32.584 us; speedup vs baseline: 1.0503x; 1.0503x over previous
//
#include <hip/hip_runtime.h>

// out[b,s,h,w] = sum_t input[b,s,t,h,w] * weight[t, h%8, w%8]   (h,w < 256; else 0)
// output[b, s*1024 + i*32 + j, q*16 + p] = out[b,s, 8i+p, 8j+q]   i,j in [0,32), p,q in [0,16)
//
// Round-15: R12 (best, 31.8us) with phase-1 load double-buffering. R12's two
// 16-deep batches had a per-slot in-flight sawtooth (16KB -> 0 -> 16KB): slot1
// loads wait for slot0 FMAs to free regs. Here: 4 chunks of 8 (A=r0 t0-7,
// B=r0 t8-15, C=r1 t0-7, D=r1 t8-15) scheduled A,B | fmaA | C | fmaB,commit0 |
// D | fmaC | fmaD,commit1 -- >=8KB/wave continuously in flight, slot1 loads
// overlap slot0 FMAs. Everything else identical to R12 (1024x256, g owns 8
// rows, half-window 16B stores, XCD swizzle).

namespace {

constexpr int TT   = 16;
constexpr int LDSW = 268;   // 264 cols + 4 pad

__device__ __forceinline__ void fma8(float4& acc, const float4* v,
                                     const float* __restrict__ wrow, int tbase) {
#pragma unroll
    for (int t = 0; t < 8; ++t) {
        const float4 wv = *reinterpret_cast<const float4*>(wrow + (tbase + t) * 64);
        acc.x += v[t].x * wv.x;
        acc.y += v[t].y * wv.y;
        acc.z += v[t].z * wv.z;
        acc.w += v[t].w * wv.w;
    }
}

__global__ __launch_bounds__(256, 4) void meas_kernel(
    const float* __restrict__ in, const float* __restrict__ wt,
    float* __restrict__ out)
{
    __shared__ float tile[8 * LDSW];
    __shared__ float wlds[TT * 64];

    const int tid = threadIdx.x;
    for (int idx = tid; idx < TT * 64; idx += 256) wlds[idx] = wt[idx];

    // zero halo cols 256..263 (c4 slots 64,65) of the 8 tile rows
    if (tid < 16) {
        const int r  = tid >> 1;
        const int c4 = 64 + (tid & 1);
        *reinterpret_cast<float4*>(&tile[r * LDSW + c4 * 4]) =
            make_float4(0.f, 0.f, 0.f, 0.f);
    }

    // XCD swizzle: 1024 blocks, 8 XCDs -> 128 logical blocks (one b) per XCD;
    // g-neighbors (output line partners) adjacent -> co-XCD, co-time.
    const int bid = (blockIdx.x & 7) * 128 + (blockIdx.x >> 3);
    const int g = bid & 31;
    const int s = (bid >> 5) & 3;
    const int b = bid >> 7;

    const float* __restrict__ inp = in + (size_t)(b * 4 + s) * TT * 65536;
    float* __restrict__ outb = out + ((size_t)b * 4096 + (size_t)s * 1024) * 256;

    // ---- Phase 1 addresses: slot0 row r0, slot1 row r0+4, col w (both slots) ----
    const int r0 = tid >> 6;          // 0..3 (wave-uniform)
    const int c  = tid & 63;
    const int w  = c * 4;
    const int hA = g * 8 + r0;        // slot0 row
    const int hB = hA + 4;            // slot1 row
    const float* gpA = inp + hA * 256 + w;
    const float* gpB = inp + hB * 256 + w;
    const float* wrowA = &wlds[(hA & 7) * 8 + (w & 7)];
    const float* wrowB = &wlds[(hB & 7) * 8 + (w & 7)];

    __syncthreads();   // weights + halo zeros visible

    float4 va[8], vb[8];
    float4 acc0 = make_float4(0.f, 0.f, 0.f, 0.f);
    float4 acc1 = make_float4(0.f, 0.f, 0.f, 0.f);

    // chunk A: slot0 t=0..7 ; chunk B: slot0 t=8..15
#pragma unroll
    for (int t = 0; t < 8; ++t) va[t] = *reinterpret_cast<const float4*>(gpA + t * 65536);
#pragma unroll
    for (int t = 0; t < 8; ++t) vb[t] = *reinterpret_cast<const float4*>(gpA + (8 + t) * 65536);
    __builtin_amdgcn_sched_barrier(0);

    fma8(acc0, va, wrowA, 0);                 // consume A (B still in flight)
    __builtin_amdgcn_sched_barrier(0);

    // chunk C: slot1 t=0..7 (reuse va regs)
#pragma unroll
    for (int t = 0; t < 8; ++t) va[t] = *reinterpret_cast<const float4*>(gpB + t * 65536);
    __builtin_amdgcn_sched_barrier(0);

    fma8(acc0, vb, wrowA, 8);                 // consume B (C in flight)
    *reinterpret_cast<float4*>(&tile[r0 * LDSW + w]) = acc0;   // commit slot0
    __builtin_amdgcn_sched_barrier(0);

    // chunk D: slot1 t=8..15 (reuse vb regs)
#pragma unroll
    for (int t = 0; t < 8; ++t) vb[t] = *reinterpret_cast<const float4*>(gpB + (8 + t) * 65536);
    __builtin_amdgcn_sched_barrier(0);

    fma8(acc1, va, wrowB, 0);                 // consume C (D in flight)
    __builtin_amdgcn_sched_barrier(0);
    fma8(acc1, vb, wrowB, 8);                 // consume D
    *reinterpret_cast<float4*>(&tile[(r0 + 4) * LDSW + w]) = acc1;   // commit slot1

    __syncthreads();

    // ---- Phase 2: half-window stores (identical to R12) ----
    // f4 unit u: j = u>>5, e = u&31, q2 = e>>1, pp = (e&1)*4.
#pragma unroll
    for (int m2 = 0; m2 < 4; ++m2) {
        const int u  = m2 * 256 + tid;
        const int j  = u >> 5;
        const int e  = u & 31;
        const int q2 = e >> 1;
        const int pp = (e & 1) * 4;
        const float* src = &tile[pp * LDSW + j * 8 + q2];
        const float4 a4 = make_float4(src[0], src[LDSW], src[2 * LDSW], src[3 * LDSW]);

        // membership 1: window-row i = g, p = pp..pp+3 (< 8)
        *reinterpret_cast<float4*>(outb + (size_t)(32 * g + j) * 256 + q2 * 16 + pp) = a4;
        // membership 2: window-row i = g-1, p = 8+pp..
        if (g > 0)
            *reinterpret_cast<float4*>(outb + (size_t)(32 * (g - 1) + j) * 256 + q2 * 16 + 8 + pp) = a4;
        // g==31: padding half (i=31, p>=8) <- image rows 256.. = zeros
        if (g == 31)
            *reinterpret_cast<float4*>(outb + (size_t)(992 + j) * 256 + q2 * 16 + 8 + pp) =
                make_float4(0.f, 0.f, 0.f, 0.f);
    }
}

} // namespace

extern "C" void kernel_launch(void* const* d_in, const int* in_sizes, int n_in,
                              void* d_out, int out_size, void* d_ws, size_t ws_size,
                              hipStream_t stream) {
    const float* in = (const float*)d_in[0];
    const float* wt = (const float*)d_in[1];
    float* out      = (float*)d_out;
    hipLaunchKernelGGL(meas_kernel, dim3(1024), dim3(256), 0, stream, in, wt, out);
}